// Round 6
// baseline (269.278 us; speedup 1.0000x reference)
//
#include <hip/hip_runtime.h>

typedef unsigned short u16;
typedef unsigned int u32;
typedef __attribute__((ext_vector_type(8))) short bf16x8;
typedef __attribute__((ext_vector_type(4))) float f32x4;

#define TOK   4096   // B*T
#define EMB   1024
#define NQKV  3072
#define TSEQ  2048
#define NH    16

__device__ __forceinline__ u16 f2b(float f) {
  union { float f; unsigned u; } v; v.f = f;
  unsigned r = v.u + 0x7FFFu + ((v.u >> 16) & 1u);
  return (u16)(r >> 16);
}

// pack bf16(a) low16, bf16(b) high16 (round half-up)
__device__ __forceinline__ u32 pack_rn(float a, float b) {
  u32 ua = __float_as_uint(a) + 0x8000u;
  u32 ub = __float_as_uint(b) + 0x8000u;
  return __builtin_amdgcn_perm(ub, ua, 0x07060302u);
}

// ---------------- fused prep: x->bf16, w_qkv^T, w_out^T ----------------
// grid = 4096 (cvt) + 768 (w_qkv 48x16) + 256 (w_out 16x16) = 5120 blocks.

__global__ __launch_bounds__(256) void prep_kernel(const float* __restrict__ x,
                                                   u16* __restrict__ x_bf,
                                                   const float* __restrict__ w_qkv,
                                                   u16* __restrict__ wqkvT,
                                                   const float* __restrict__ w_out,
                                                   u16* __restrict__ woutT) {
  __shared__ u16 sm[64][65];
  int bid = blockIdx.x, tid = threadIdx.x;
  if (bid < 4096) {                       // cvt: 1M float4 elements
    int i = bid * 256 + tid;
    float4 v = ((const float4*)x)[i];
    union { u16 us[4]; uint2 u2; } o;
    o.us[0] = f2b(v.x); o.us[1] = f2b(v.y); o.us[2] = f2b(v.z); o.us[3] = f2b(v.w);
    ((uint2*)x_bf)[i] = o.u2;
    return;
  }
  const float* src; u16* dst; int R, C, bx, by;
  if (bid < 4096 + 768) {                 // w_qkv: [1024][3072] -> [3072][1024]
    int t = bid - 4096; bx = t % 48; by = t / 48;
    src = w_qkv; dst = wqkvT; R = EMB; C = NQKV;
  } else {                                // w_out: [1024][1024] -> [1024][1024]
    int t = bid - 4096 - 768; bx = t & 15; by = t >> 4;
    src = w_out; dst = woutT; R = EMB; C = EMB;
  }
  int c0 = bx * 64, r0 = by * 64;
#pragma unroll
  for (int i = 0; i < 16; i++) {
    int idx = tid + i * 256;
    int r = idx >> 6, c = idx & 63;
    sm[r][c] = f2b(src[(size_t)(r0 + r) * C + c0 + c]);
  }
  __syncthreads();
#pragma unroll
  for (int i = 0; i < 16; i++) {
    int idx = tid + i * 256;
    int cc = idx >> 6, rr = idx & 63;
    dst[(size_t)(c0 + cc) * R + r0 + rr] = sm[rr][cc];
  }
}

// per-head transpose: V[bh][t][d] -> Vt[bh][d][t]
__global__ __launch_bounds__(256) void transpose_v(const u16* __restrict__ V,
                                                   u16* __restrict__ Vt) {
  __shared__ u16 sm[64][72];
  int t0 = blockIdx.x * 64, bh = blockIdx.y;
  size_t base = (size_t)bh * TSEQ * 64;
  int tid = threadIdx.x;
  int r = tid >> 2, c = (tid & 3) * 16;
  *(bf16x8*)&sm[r][c]     = *(const bf16x8*)&V[base + (size_t)(t0 + r) * 64 + c];
  *(bf16x8*)&sm[r][c + 8] = *(const bf16x8*)&V[base + (size_t)(t0 + r) * 64 + c + 8];
  __syncthreads();
  int d = tid >> 2, tc = (tid & 3) * 16;
  union { u16 us[16]; uint4 v4[2]; } o;
#pragma unroll
  for (int i = 0; i < 16; i++) o.us[i] = sm[tc + i][d];
  *(uint4*)&Vt[base + (size_t)d * TSEQ + t0 + tc]     = o.v4[0];
  *(uint4*)&Vt[base + (size_t)d * TSEQ + t0 + tc + 8] = o.v4[1];
}

// ---------------- GEMM: C[m][n] = sum_k A[m][k]*Bt[n][k] + bias[n] ----------------
// Stride-68 LDS (<=2-way bank aliasing, free) + register-staged tiles with
// cross-iteration prefetch. C^T orientation -> vectorized epilogue.
// MODE 0: uint2 bf16 scatter into Q/K/V [bh][t][d].  MODE 1: float4 fp32 [M][N].

template <int MODE, int TM>
__global__ __launch_bounds__(256) void gemm_bt(const u16* __restrict__ A,
                                               const u16* __restrict__ Bt,
                                               const float* __restrict__ bias,
                                               u16* __restrict__ qb, u16* __restrict__ kb,
                                               u16* __restrict__ vb, float* __restrict__ outp,
                                               int K, int N) {
  constexpr int LDA = 68;
  constexpr int CT = (TM == 128) ? 4 : 2;
  constexpr int AC = TM / 32;
  __shared__ u16 As[TM][LDA];
  __shared__ u16 Bs[128][LDA];
  int tid = threadIdx.x;
  int m0 = blockIdx.y * TM, n0 = blockIdx.x * 128;
  int lane = tid & 63, wid = tid >> 6;
  int wm = (TM == 128) ? (wid >> 1) * 64 : 0;
  int wn = (TM == 128) ? (wid & 1) * 64 : wid * 32;
  int l15 = lane & 15, quad = lane >> 4;
  int lrow = lane >> 3, lcol = (lane & 7) * 8;

  f32x4 acc[4][CT];
#pragma unroll
  for (int i = 0; i < 4; i++)
#pragma unroll
    for (int j = 0; j < CT; j++) acc[i][j] = (f32x4){0.f, 0.f, 0.f, 0.f};

  bf16x8 ar[AC], br[4];
#pragma unroll
  for (int i = 0; i < AC; i++)
    ar[i] = *(const bf16x8*)&A[(size_t)(m0 + (wid * AC + i) * 8 + lrow) * K + lcol];
#pragma unroll
  for (int i = 0; i < 4; i++)
    br[i] = *(const bf16x8*)&Bt[(size_t)(n0 + (wid * 4 + i) * 8 + lrow) * K + lcol];

  for (int k0 = 0; k0 < K; k0 += 64) {
#pragma unroll
    for (int i = 0; i < AC; i++)
      *(bf16x8*)&As[(wid * AC + i) * 8 + lrow][lcol] = ar[i];
#pragma unroll
    for (int i = 0; i < 4; i++)
      *(bf16x8*)&Bs[(wid * 4 + i) * 8 + lrow][lcol] = br[i];
    __syncthreads();

    if (k0 + 64 < K) {
      int kn = k0 + 64;
#pragma unroll
      for (int i = 0; i < AC; i++)
        ar[i] = *(const bf16x8*)&A[(size_t)(m0 + (wid * AC + i) * 8 + lrow) * K + kn + lcol];
#pragma unroll
      for (int i = 0; i < 4; i++)
        br[i] = *(const bf16x8*)&Bt[(size_t)(n0 + (wid * 4 + i) * 8 + lrow) * K + kn + lcol];
    }

#pragma unroll
    for (int ks = 0; ks < 2; ks++) {
      bf16x8 af[4], bfr[CT];
#pragma unroll
      for (int rt = 0; rt < 4; rt++)
        af[rt] = *(const bf16x8*)&As[wm + rt * 16 + l15][ks * 32 + quad * 8];
#pragma unroll
      for (int ct = 0; ct < CT; ct++)
        bfr[ct] = *(const bf16x8*)&Bs[wn + ct * 16 + l15][ks * 32 + quad * 8];
#pragma unroll
      for (int rt = 0; rt < 4; rt++)
#pragma unroll
        for (int ct = 0; ct < CT; ct++)
          acc[rt][ct] = __builtin_amdgcn_mfma_f32_16x16x32_bf16(bfr[ct], af[rt], acc[rt][ct], 0, 0, 0);
    }
    __syncthreads();
  }

#pragma unroll
  for (int rt = 0; rt < 4; rt++) {
#pragma unroll
    for (int ct = 0; ct < CT; ct++) {
      int m = m0 + wm + rt * 16 + l15;
      int nb = n0 + wn + ct * 16 + quad * 4;
      float4 b4 = *(const float4*)&bias[nb];
      float v0 = acc[rt][ct][0] + b4.x, v1 = acc[rt][ct][1] + b4.y;
      float v2 = acc[rt][ct][2] + b4.z, v3 = acc[rt][ct][3] + b4.w;
      if (MODE == 0) {
        int sel = nb >> 10;
        int c = nb & 1023;
        int h = c >> 6, d0 = c & 63;
        int b = m >> 11, t = m & 2047;
        u16* dst = (sel == 0) ? qb : (sel == 1) ? kb : vb;
        union { u32 u[2]; uint2 u2; } o;
        o.u[0] = pack_rn(v0, v1);
        o.u[1] = pack_rn(v2, v3);
        *(uint2*)&dst[((((size_t)b * NH + h) * TSEQ + t) << 6) + d0] = o.u2;
      } else {
        float4 o = {v0, v1, v2, v3};
        *(float4*)&outp[(size_t)m * N + nb] = o;
      }
    }
  }
}

// ---------------- flash attention: direct-from-global K/V fragments ----------------
// No LDS for K/V (fragment layout loads straight from global; L1 absorbs the
// 4-waves-per-block redundancy). Only LDS use is the wave-private P transpose
// slab -> the kernel is barrier-free. Fixed-M softmax (exact, shift-invariant).
// grid 1024; qt swizzled so each CU's 4 blocks have complementary lengths.

__global__ __launch_bounds__(256) void attn_kernel(const u16* __restrict__ Qb,
                                                   const u16* __restrict__ Kb,
                                                   const u16* __restrict__ Vtb,
                                                   u16* __restrict__ O) {
  __shared__ u16 Ps[4][16][68];

  const float SCL = 0.18033688f;   // (1/8) * log2(e)
  const float MOFF = 16.0f;

  int id = blockIdx.x;
  int bh = (id >> 5) & 31;
  int q5 = id & 31;
  int qt = ((id >> 8) & 1) ? (31 - q5) : q5;

  int tid = threadIdx.x, lane = tid & 63, w = tid >> 6;
  int l15 = lane & 15, quad = lane >> 4;
  const size_t hoff = (size_t)bh * TSEQ * 64;

  int qrow = qt * 64 + w * 16 + l15;
  bf16x8 qf[2];
  qf[0] = *(const bf16x8*)&Qb[hoff + (size_t)qrow * 64 + quad * 8];
  qf[1] = *(const bf16x8*)&Qb[hoff + (size_t)qrow * 64 + 32 + quad * 8];

  f32x4 acc[4];
#pragma unroll
  for (int i = 0; i < 4; i++) acc[i] = (f32x4){0.f, 0.f, 0.f, 0.f};
  float l_i = 0.f;

  // per-lane base pointers for fragment loads (advanced by constants per iter)
  const u16* kp = Kb + hoff + (size_t)l15 * 64 + quad * 8;          // + ct*16*64, +32
  const u16* vp = Vtb + hoff + (size_t)l15 * TSEQ + quad * 8;       // + dt*16*TSEQ, +32

  for (int kt = 0; kt <= qt; kt++) {
    // S^T = K Q^T : lane l15 = q, key = ct*16 + quad*4 + r
    f32x4 s[4];
#pragma unroll
    for (int ct = 0; ct < 4; ct++) {
      bf16x8 kf0 = *(const bf16x8*)&kp[ct * 16 * 64];
      bf16x8 kf1 = *(const bf16x8*)&kp[ct * 16 * 64 + 32];
      f32x4 z = (f32x4){0.f, 0.f, 0.f, 0.f};
      z = __builtin_amdgcn_mfma_f32_16x16x32_bf16(kf0, qf[0], z, 0, 0, 0);
      s[ct] = __builtin_amdgcn_mfma_f32_16x16x32_bf16(kf1, qf[1], z, 0, 0, 0);
    }

    if (kt == qt) {                        // causal mask only on diagonal tile
      int ql = w * 16 + l15;
#pragma unroll
      for (int ct = 0; ct < 4; ct++)
#pragma unroll
        for (int r = 0; r < 4; r++)
          if (ct * 16 + quad * 4 + r > ql) s[ct][r] = -1e30f;
    }

    float rs = 0.f;
#pragma unroll
    for (int ct = 0; ct < 4; ct++)
#pragma unroll
      for (int r = 0; r < 4; r++) {
        float p = exp2f(__builtin_fmaf(s[ct][r], SCL, -MOFF));
        s[ct][r] = p;
        rs += p;
      }
    l_i += rs;

    // P^T (C-layout) -> B-operand layout via wave-private LDS slab (no barrier)
#pragma unroll
    for (int ct = 0; ct < 4; ct++) {
      union { u32 u[2]; uint2 u2; } o;
      o.u[0] = pack_rn(s[ct][0], s[ct][1]);
      o.u[1] = pack_rn(s[ct][2], s[ct][3]);
      *(uint2*)&Ps[w][l15][ct * 16 + quad * 4] = o.u2;
    }
    bf16x8 pf0 = *(const bf16x8*)&Ps[w][l15][quad * 8];
    bf16x8 pf1 = *(const bf16x8*)&Ps[w][l15][32 + quad * 8];
#pragma unroll
    for (int dt = 0; dt < 4; dt++) {
      bf16x8 vf0 = *(const bf16x8*)&vp[(size_t)dt * 16 * TSEQ];
      bf16x8 vf1 = *(const bf16x8*)&vp[(size_t)dt * 16 * TSEQ + 32];
      acc[dt] = __builtin_amdgcn_mfma_f32_16x16x32_bf16(vf0, pf0, acc[dt], 0, 0, 0);
      acc[dt] = __builtin_amdgcn_mfma_f32_16x16x32_bf16(vf1, pf1, acc[dt], 0, 0, 0);
    }

    kp += 64 * 64;                         // next K tile (64 rows)
    vp += 64;                              // next V^T column block
  }

  l_i += __shfl_xor(l_i, 16);
  l_i += __shfl_xor(l_i, 32);
  float inv = 1.0f / l_i;

  int b = bh >> 4, h = bh & 15;
  int qg = qt * 64 + w * 16 + l15;
  size_t rowbase = ((size_t)b * TSEQ + qg) * 1024 + h * 64;
#pragma unroll
  for (int dt = 0; dt < 4; dt++) {
    union { u32 u[2]; uint2 u2; } o;
    o.u[0] = pack_rn(acc[dt][0] * inv, acc[dt][1] * inv);
    o.u[1] = pack_rn(acc[dt][2] * inv, acc[dt][3] * inv);
    *(uint2*)&O[rowbase + dt * 16 + quad * 4] = o.u2;
  }
}

// ---------------- launch ----------------

extern "C" void kernel_launch(void* const* d_in, const int* in_sizes, int n_in,
                              void* d_out, int out_size, void* d_ws, size_t ws_size,
                              hipStream_t stream) {
  (void)in_sizes; (void)n_in; (void)out_size; (void)ws_size;
  const float* x     = (const float*)d_in[0];
  const float* w_qkv = (const float*)d_in[1];
  const float* b_qkv = (const float*)d_in[2];
  const float* w_out = (const float*)d_in[3];
  const float* b_out = (const float*)d_in[4];
  float* out = (float*)d_out;

  char* p = (char*)d_ws;
  u16* x_bf  = (u16*)p; p += (size_t)TOK * EMB * 2;       // 8 MiB (dead after gemm0)
  u16* wqkvT = (u16*)p; p += (size_t)NQKV * EMB * 2;      // 6 MiB
  u16* woutT = (u16*)p; p += (size_t)EMB * EMB * 2;       // 2 MiB
  u16* Qb    = (u16*)p; p += (size_t)32 * TSEQ * 64 * 2;  // 8 MiB  [bh][t][d]
  u16* Kb    = (u16*)p; p += (size_t)32 * TSEQ * 64 * 2;  //        [bh][t][d]
  u16* Vraw  = (u16*)p; p += (size_t)32 * TSEQ * 64 * 2;  //        [bh][t][d]
  u16* attn_o = (u16*)p;                                  // 8 MiB
  u16* Vtb   = x_bf;   // alias: x_bf dead once gemm0 completes (stream-ordered)

  prep_kernel<<<dim3(4096 + 768 + 256), 256, 0, stream>>>(x, x_bf, w_qkv, wqkvT, w_out, woutT);
  gemm_bt<0, 128><<<dim3(NQKV / 128, TOK / 128), 256, 0, stream>>>(x_bf, wqkvT, b_qkv,
                                                                   Qb, Kb, Vraw, nullptr, EMB, NQKV);
  transpose_v<<<dim3(TSEQ / 64, 32), 256, 0, stream>>>(Vraw, Vtb);
  attn_kernel<<<dim3(1024), 256, 0, stream>>>(Qb, Kb, Vtb, attn_o);
  gemm_bt<1, 64><<<dim3(EMB / 128, TOK / 64), 256, 0, stream>>>(attn_o, woutT, b_out,
                                                                nullptr, nullptr, nullptr, out, EMB, EMB);
}

// Round 7
// 200.572 us; speedup vs baseline: 1.3426x; 1.3426x over previous
//
#include <hip/hip_runtime.h>

typedef unsigned short u16;
typedef unsigned int u32;
typedef __attribute__((ext_vector_type(8))) short bf16x8;
typedef __attribute__((ext_vector_type(4))) float f32x4;

#define TOK   4096   // B*T
#define EMB   1024
#define NQKV  3072
#define TSEQ  2048
#define NH    16

__device__ __forceinline__ u16 f2b(float f) {
  union { float f; unsigned u; } v; v.f = f;
  unsigned r = v.u + 0x7FFFu + ((v.u >> 16) & 1u);
  return (u16)(r >> 16);
}

// pack bf16(a) low16, bf16(b) high16 (round half-up)
__device__ __forceinline__ u32 pack_rn(float a, float b) {
  u32 ua = __float_as_uint(a) + 0x8000u;
  u32 ub = __float_as_uint(b) + 0x8000u;
  return __builtin_amdgcn_perm(ub, ua, 0x07060302u);
}

// ---------------- fused prep: x->bf16, w_qkv^T, w_out^T ----------------

__global__ __launch_bounds__(256) void prep_kernel(const float* __restrict__ x,
                                                   u16* __restrict__ x_bf,
                                                   const float* __restrict__ w_qkv,
                                                   u16* __restrict__ wqkvT,
                                                   const float* __restrict__ w_out,
                                                   u16* __restrict__ woutT) {
  __shared__ u16 sm[64][65];
  int bid = blockIdx.x, tid = threadIdx.x;
  if (bid < 4096) {                       // cvt: 1M float4 elements
    int i = bid * 256 + tid;
    float4 v = ((const float4*)x)[i];
    union { u16 us[4]; uint2 u2; } o;
    o.us[0] = f2b(v.x); o.us[1] = f2b(v.y); o.us[2] = f2b(v.z); o.us[3] = f2b(v.w);
    ((uint2*)x_bf)[i] = o.u2;
    return;
  }
  const float* src; u16* dst; int R, C, bx, by;
  if (bid < 4096 + 768) {                 // w_qkv: [1024][3072] -> [3072][1024]
    int t = bid - 4096; bx = t % 48; by = t / 48;
    src = w_qkv; dst = wqkvT; R = EMB; C = NQKV;
  } else {                                // w_out: [1024][1024] -> [1024][1024]
    int t = bid - 4096 - 768; bx = t & 15; by = t >> 4;
    src = w_out; dst = woutT; R = EMB; C = EMB;
  }
  int c0 = bx * 64, r0 = by * 64;
#pragma unroll
  for (int i = 0; i < 16; i++) {
    int idx = tid + i * 256;
    int r = idx >> 6, c = idx & 63;
    sm[r][c] = f2b(src[(size_t)(r0 + r) * C + c0 + c]);
  }
  __syncthreads();
#pragma unroll
  for (int i = 0; i < 16; i++) {
    int idx = tid + i * 256;
    int cc = idx >> 6, rr = idx & 63;
    dst[(size_t)(c0 + cc) * R + r0 + rr] = sm[rr][cc];
  }
}

// per-head transpose: V[bh][t][d] -> Vt[bh][d][t]
__global__ __launch_bounds__(256) void transpose_v(const u16* __restrict__ V,
                                                   u16* __restrict__ Vt) {
  __shared__ u16 sm[64][72];
  int t0 = blockIdx.x * 64, bh = blockIdx.y;
  size_t base = (size_t)bh * TSEQ * 64;
  int tid = threadIdx.x;
  int r = tid >> 2, c = (tid & 3) * 16;
  *(bf16x8*)&sm[r][c]     = *(const bf16x8*)&V[base + (size_t)(t0 + r) * 64 + c];
  *(bf16x8*)&sm[r][c + 8] = *(const bf16x8*)&V[base + (size_t)(t0 + r) * 64 + c + 8];
  __syncthreads();
  int d = tid >> 2, tc = (tid & 3) * 16;
  union { u16 us[16]; uint4 v4[2]; } o;
#pragma unroll
  for (int i = 0; i < 16; i++) o.us[i] = sm[tc + i][d];
  *(uint4*)&Vt[base + (size_t)d * TSEQ + t0 + tc]     = o.v4[0];
  *(uint4*)&Vt[base + (size_t)d * TSEQ + t0 + tc + 8] = o.v4[1];
}

// ---------------- GEMM: C[m][n] = sum_k A[m][k]*Bt[n][k] + bias[n] ----------------
// Stride-68 LDS (<=2-way bank aliasing, free) + register-staged tiles with
// cross-iteration prefetch. C^T orientation -> vectorized epilogue.
// MODE 0: uint2 bf16 scatter into Q/K/V [bh][t][d].  MODE 1: float4 fp32 [M][N].

template <int MODE, int TM>
__global__ __launch_bounds__(256) void gemm_bt(const u16* __restrict__ A,
                                               const u16* __restrict__ Bt,
                                               const float* __restrict__ bias,
                                               u16* __restrict__ qb, u16* __restrict__ kb,
                                               u16* __restrict__ vb, float* __restrict__ outp,
                                               int K, int N) {
  constexpr int LDA = 68;
  constexpr int CT = (TM == 128) ? 4 : 2;
  constexpr int AC = TM / 32;
  __shared__ u16 As[TM][LDA];
  __shared__ u16 Bs[128][LDA];
  int tid = threadIdx.x;
  int m0 = blockIdx.y * TM, n0 = blockIdx.x * 128;
  int lane = tid & 63, wid = tid >> 6;
  int wm = (TM == 128) ? (wid >> 1) * 64 : 0;
  int wn = (TM == 128) ? (wid & 1) * 64 : wid * 32;
  int l15 = lane & 15, quad = lane >> 4;
  int lrow = lane >> 3, lcol = (lane & 7) * 8;

  f32x4 acc[4][CT];
#pragma unroll
  for (int i = 0; i < 4; i++)
#pragma unroll
    for (int j = 0; j < CT; j++) acc[i][j] = (f32x4){0.f, 0.f, 0.f, 0.f};

  bf16x8 ar[AC], br[4];
#pragma unroll
  for (int i = 0; i < AC; i++)
    ar[i] = *(const bf16x8*)&A[(size_t)(m0 + (wid * AC + i) * 8 + lrow) * K + lcol];
#pragma unroll
  for (int i = 0; i < 4; i++)
    br[i] = *(const bf16x8*)&Bt[(size_t)(n0 + (wid * 4 + i) * 8 + lrow) * K + lcol];

  for (int k0 = 0; k0 < K; k0 += 64) {
#pragma unroll
    for (int i = 0; i < AC; i++)
      *(bf16x8*)&As[(wid * AC + i) * 8 + lrow][lcol] = ar[i];
#pragma unroll
    for (int i = 0; i < 4; i++)
      *(bf16x8*)&Bs[(wid * 4 + i) * 8 + lrow][lcol] = br[i];
    __syncthreads();

    if (k0 + 64 < K) {
      int kn = k0 + 64;
#pragma unroll
      for (int i = 0; i < AC; i++)
        ar[i] = *(const bf16x8*)&A[(size_t)(m0 + (wid * AC + i) * 8 + lrow) * K + kn + lcol];
#pragma unroll
      for (int i = 0; i < 4; i++)
        br[i] = *(const bf16x8*)&Bt[(size_t)(n0 + (wid * 4 + i) * 8 + lrow) * K + kn + lcol];
    }

#pragma unroll
    for (int ks = 0; ks < 2; ks++) {
      bf16x8 af[4], bfr[CT];
#pragma unroll
      for (int rt = 0; rt < 4; rt++)
        af[rt] = *(const bf16x8*)&As[wm + rt * 16 + l15][ks * 32 + quad * 8];
#pragma unroll
      for (int ct = 0; ct < CT; ct++)
        bfr[ct] = *(const bf16x8*)&Bs[wn + ct * 16 + l15][ks * 32 + quad * 8];
#pragma unroll
      for (int rt = 0; rt < 4; rt++)
#pragma unroll
        for (int ct = 0; ct < CT; ct++)
          acc[rt][ct] = __builtin_amdgcn_mfma_f32_16x16x32_bf16(bfr[ct], af[rt], acc[rt][ct], 0, 0, 0);
    }
    __syncthreads();
  }

#pragma unroll
  for (int rt = 0; rt < 4; rt++) {
#pragma unroll
    for (int ct = 0; ct < CT; ct++) {
      int m = m0 + wm + rt * 16 + l15;
      int nb = n0 + wn + ct * 16 + quad * 4;
      float4 b4 = *(const float4*)&bias[nb];
      float v0 = acc[rt][ct][0] + b4.x, v1 = acc[rt][ct][1] + b4.y;
      float v2 = acc[rt][ct][2] + b4.z, v3 = acc[rt][ct][3] + b4.w;
      if (MODE == 0) {
        int sel = nb >> 10;
        int c = nb & 1023;
        int h = c >> 6, d0 = c & 63;
        int b = m >> 11, t = m & 2047;
        u16* dst = (sel == 0) ? qb : (sel == 1) ? kb : vb;
        union { u32 u[2]; uint2 u2; } o;
        o.u[0] = pack_rn(v0, v1);
        o.u[1] = pack_rn(v2, v3);
        *(uint2*)&dst[((((size_t)b * NH + h) * TSEQ + t) << 6) + d0] = o.u2;
      } else {
        float4 o = {v0, v1, v2, v3};
        *(float4*)&outp[(size_t)m * N + nb] = o;
      }
    }
  }
}

// ---------------- flash attention: 2 q-subtiles per wave ----------------
// Block = 4 waves x 32 q-rows = 128 q-rows; grid 512 = 16 Qt x 32 bh, Qt
// swizzled so CU pairs (id, id+256) have Qt summing to 15 (balanced makespan).
// K/V staged in stride-68 LDS (conflict-free); each K/V fragment read is shared
// by the wave's TWO q-subtile MFMA chains -> halves the block's redundant LDS
// reads vs 16-row waves, doubles per-wave ILP. Fixed-M softmax (exact).

__global__ __launch_bounds__(256) void attn_kernel(const u16* __restrict__ Qb,
                                                   const u16* __restrict__ Kb,
                                                   const u16* __restrict__ Vtb,
                                                   u16* __restrict__ O) {
  __shared__ u16 Ks[64][68];
  __shared__ u16 Vt[64][68];
  __shared__ u16 Ps[4][2][16][68];

  const float SCL = 0.18033688f;   // (1/8) * log2(e)
  const float MOFF = 16.0f;

  int id = blockIdx.x;
  int bh = id & 31;
  int qq = id >> 5;                        // 0..15
  int Qt = (qq < 8) ? qq : 23 - qq;        // pair (id,id+256): Qt sums to 15

  int tid = threadIdx.x, lane = tid & 63, w = tid >> 6;
  int l15 = lane & 15, quad = lane >> 4;
  const size_t hoff = (size_t)bh * TSEQ * 64;

  int q0 = Qt * 128 + w * 32;              // wave's first q row (sub0); sub1 = +16
  bf16x8 qfA0, qfA1, qfB0, qfB1;
  {
    const u16* qp = Qb + hoff + (size_t)(q0 + l15) * 64 + quad * 8;
    qfA0 = *(const bf16x8*)qp;
    qfA1 = *(const bf16x8*)(qp + 32);
    qfB0 = *(const bf16x8*)(qp + 16 * 64);
    qfB1 = *(const bf16x8*)(qp + 16 * 64 + 32);
  }

  f32x4 accA[4], accB[4];
#pragma unroll
  for (int i = 0; i < 4; i++) {
    accA[i] = (f32x4){0.f, 0.f, 0.f, 0.f};
    accB[i] = (f32x4){0.f, 0.f, 0.f, 0.f};
  }
  float lA = 0.f, lB = 0.f;

  int srow = tid >> 2, scol = (tid & 3) * 16;
  const int KT = 2 * Qt + 2;               // k tiles (64 keys each)

  // prefetch tile 0
  bf16x8 kr0, kr1, vr0, vr1;
  {
    size_t kg = hoff + (size_t)srow * 64;
    kr0 = *(const bf16x8*)&Kb[kg + scol];
    kr1 = *(const bf16x8*)&Kb[kg + scol + 8];
    size_t vg = hoff + (size_t)srow * TSEQ;
    vr0 = *(const bf16x8*)&Vtb[vg + scol];
    vr1 = *(const bf16x8*)&Vtb[vg + scol + 8];
  }

  for (int kt = 0; kt < KT; kt++) {
    __syncthreads();                       // prev iter's readers done
    *(bf16x8*)&Ks[srow][scol]     = kr0;
    *(bf16x8*)&Ks[srow][scol + 8] = kr1;
    *(bf16x8*)&Vt[srow][scol]     = vr0;
    *(bf16x8*)&Vt[srow][scol + 8] = vr1;
    __syncthreads();                       // tile visible
    if (kt + 1 < KT) {                     // prefetch next tile; overlaps compute
      size_t kg = hoff + (size_t)((kt + 1) * 64 + srow) * 64;
      kr0 = *(const bf16x8*)&Kb[kg + scol];
      kr1 = *(const bf16x8*)&Kb[kg + scol + 8];
      size_t vg = hoff + (size_t)srow * TSEQ + (kt + 1) * 64;
      vr0 = *(const bf16x8*)&Vtb[vg + scol];
      vr1 = *(const bf16x8*)&Vtb[vg + scol + 8];
    }

    // S^T = K Q^T for both subtiles; K fragments loaded ONCE, used twice
    f32x4 sA[4], sB[4];
#pragma unroll
    for (int ct = 0; ct < 4; ct++) {
      bf16x8 kf0 = *(const bf16x8*)&Ks[ct * 16 + l15][quad * 8];
      bf16x8 kf1 = *(const bf16x8*)&Ks[ct * 16 + l15][32 + quad * 8];
      f32x4 z = (f32x4){0.f, 0.f, 0.f, 0.f};
      z = __builtin_amdgcn_mfma_f32_16x16x32_bf16(kf0, qfA0, z, 0, 0, 0);
      sA[ct] = __builtin_amdgcn_mfma_f32_16x16x32_bf16(kf1, qfA1, z, 0, 0, 0);
      f32x4 y = (f32x4){0.f, 0.f, 0.f, 0.f};
      y = __builtin_amdgcn_mfma_f32_16x16x32_bf16(kf0, qfB0, y, 0, 0, 0);
      sB[ct] = __builtin_amdgcn_mfma_f32_16x16x32_bf16(kf1, qfB1, y, 0, 0, 0);
    }

    // causal mask — only tiles crossing the wave's diagonal band (wave-uniform tests)
    int kbase = kt * 64;
    if (kbase + 63 > q0) {                 // sub0
      int qg = q0 + l15;
#pragma unroll
      for (int ct = 0; ct < 4; ct++)
#pragma unroll
        for (int r = 0; r < 4; r++)
          if (kbase + ct * 16 + quad * 4 + r > qg) sA[ct][r] = -1e30f;
    }
    if (kbase + 63 > q0 + 16) {            // sub1
      int qg = q0 + 16 + l15;
#pragma unroll
      for (int ct = 0; ct < 4; ct++)
#pragma unroll
        for (int r = 0; r < 4; r++)
          if (kbase + ct * 16 + quad * 4 + r > qg) sB[ct][r] = -1e30f;
    }

    float rsA = 0.f, rsB = 0.f;
#pragma unroll
    for (int ct = 0; ct < 4; ct++)
#pragma unroll
      for (int r = 0; r < 4; r++) {
        float pA = exp2f(__builtin_fmaf(sA[ct][r], SCL, -MOFF));
        float pB = exp2f(__builtin_fmaf(sB[ct][r], SCL, -MOFF));
        sA[ct][r] = pA; rsA += pA;
        sB[ct][r] = pB; rsB += pB;
      }
    lA += rsA; lB += rsB;

    // P^T (C-layout) -> B-operand layout via wave-private LDS (no barrier)
#pragma unroll
    for (int ct = 0; ct < 4; ct++) {
      union { u32 u[2]; uint2 u2; } oa, ob;
      oa.u[0] = pack_rn(sA[ct][0], sA[ct][1]);
      oa.u[1] = pack_rn(sA[ct][2], sA[ct][3]);
      ob.u[0] = pack_rn(sB[ct][0], sB[ct][1]);
      ob.u[1] = pack_rn(sB[ct][2], sB[ct][3]);
      *(uint2*)&Ps[w][0][l15][ct * 16 + quad * 4] = oa.u2;
      *(uint2*)&Ps[w][1][l15][ct * 16 + quad * 4] = ob.u2;
    }
    bf16x8 pfA0 = *(const bf16x8*)&Ps[w][0][l15][quad * 8];
    bf16x8 pfA1 = *(const bf16x8*)&Ps[w][0][l15][32 + quad * 8];
    bf16x8 pfB0 = *(const bf16x8*)&Ps[w][1][l15][quad * 8];
    bf16x8 pfB1 = *(const bf16x8*)&Ps[w][1][l15][32 + quad * 8];

    // O^T += V^T P ; V fragments loaded ONCE, used twice
#pragma unroll
    for (int dt = 0; dt < 4; dt++) {
      bf16x8 vf0 = *(const bf16x8*)&Vt[dt * 16 + l15][quad * 8];
      bf16x8 vf1 = *(const bf16x8*)&Vt[dt * 16 + l15][32 + quad * 8];
      accA[dt] = __builtin_amdgcn_mfma_f32_16x16x32_bf16(vf0, pfA0, accA[dt], 0, 0, 0);
      accA[dt] = __builtin_amdgcn_mfma_f32_16x16x32_bf16(vf1, pfA1, accA[dt], 0, 0, 0);
      accB[dt] = __builtin_amdgcn_mfma_f32_16x16x32_bf16(vf0, pfB0, accB[dt], 0, 0, 0);
      accB[dt] = __builtin_amdgcn_mfma_f32_16x16x32_bf16(vf1, pfB1, accB[dt], 0, 0, 0);
    }
  }

  lA += __shfl_xor(lA, 16); lA += __shfl_xor(lA, 32);
  lB += __shfl_xor(lB, 16); lB += __shfl_xor(lB, 32);
  float invA = 1.0f / lA, invB = 1.0f / lB;

  int b = bh >> 4, h = bh & 15;
  size_t rowA = ((size_t)b * TSEQ + q0 + l15) * 1024 + h * 64;
  size_t rowB = rowA + (size_t)16 * 1024;
#pragma unroll
  for (int dt = 0; dt < 4; dt++) {
    union { u32 u[2]; uint2 u2; } oa, ob;
    oa.u[0] = pack_rn(accA[dt][0] * invA, accA[dt][1] * invA);
    oa.u[1] = pack_rn(accA[dt][2] * invA, accA[dt][3] * invA);
    ob.u[0] = pack_rn(accB[dt][0] * invB, accB[dt][1] * invB);
    ob.u[1] = pack_rn(accB[dt][2] * invB, accB[dt][3] * invB);
    *(uint2*)&O[rowA + dt * 16 + quad * 4] = oa.u2;
    *(uint2*)&O[rowB + dt * 16 + quad * 4] = ob.u2;
  }
}

// ---------------- launch ----------------

extern "C" void kernel_launch(void* const* d_in, const int* in_sizes, int n_in,
                              void* d_out, int out_size, void* d_ws, size_t ws_size,
                              hipStream_t stream) {
  (void)in_sizes; (void)n_in; (void)out_size; (void)ws_size;
  const float* x     = (const float*)d_in[0];
  const float* w_qkv = (const float*)d_in[1];
  const float* b_qkv = (const float*)d_in[2];
  const float* w_out = (const float*)d_in[3];
  const float* b_out = (const float*)d_in[4];
  float* out = (float*)d_out;

  char* p = (char*)d_ws;
  u16* x_bf  = (u16*)p; p += (size_t)TOK * EMB * 2;       // 8 MiB (dead after gemm0)
  u16* wqkvT = (u16*)p; p += (size_t)NQKV * EMB * 2;      // 6 MiB
  u16* woutT = (u16*)p; p += (size_t)EMB * EMB * 2;       // 2 MiB
  u16* Qb    = (u16*)p; p += (size_t)32 * TSEQ * 64 * 2;  // 8 MiB  [bh][t][d]
  u16* Kb    = (u16*)p; p += (size_t)32 * TSEQ * 64 * 2;  //        [bh][t][d]
  u16* Vraw  = (u16*)p; p += (size_t)32 * TSEQ * 64 * 2;  //        [bh][t][d]
  u16* attn_o = (u16*)p;                                  // 8 MiB
  u16* Vtb   = x_bf;   // alias: x_bf dead once gemm0 completes (stream-ordered)

  prep_kernel<<<dim3(4096 + 768 + 256), 256, 0, stream>>>(x, x_bf, w_qkv, wqkvT, w_out, woutT);
  gemm_bt<0, 128><<<dim3(NQKV / 128, TOK / 128), 256, 0, stream>>>(x_bf, wqkvT, b_qkv,
                                                                   Qb, Kb, Vraw, nullptr, EMB, NQKV);
  transpose_v<<<dim3(TSEQ / 64, 32), 256, 0, stream>>>(Vraw, Vtb);
  attn_kernel<<<dim3(512), 256, 0, stream>>>(Qb, Kb, Vtb, attn_o);
  gemm_bt<1, 64><<<dim3(EMB / 128, TOK / 64), 256, 0, stream>>>(attn_o, woutT, b_out,
                                                                nullptr, nullptr, nullptr, out, EMB, EMB);
}